// Round 1
// baseline (357.040 us; speedup 1.0000x reference)
//
#include <hip/hip_runtime.h>

#define NFEAT 256
#define DHEAD 64
#define NSEQ  4096

constexpr float NORM_C  = 0.35355339059327373f;  // 64^-0.25
constexpr float RATIO_C = 0.0625f;               // 256^-0.5
constexpr float DIAG_C  = 0.0625f;               // 0.5 * 64^-0.5
constexpr float KEPS_C  = 1e-4f;

using v8s = __attribute__((ext_vector_type(8))) short;
using v4f = __attribute__((ext_vector_type(4))) float;
union Frag8 { v8s v; ushort u[8]; };

__device__ __forceinline__ ushort bf16h(float x) {
  unsigned u = __float_as_uint(x);
  return (ushort)((u + 0x7FFFu + ((u >> 16) & 1)) >> 16);
}
__device__ __forceinline__ float bf16f(ushort h) {
  return __uint_as_float(((unsigned)h) << 16);
}
__device__ __forceinline__ unsigned enc_f(float f) {
  unsigned u = __float_as_uint(f);
  return (u & 0x80000000u) ? ~u : (u | 0x80000000u);
}
__device__ __forceinline__ float dec_f(unsigned e) {
  return (e & 0x80000000u) ? __uint_as_float(e ^ 0x80000000u) : __uint_as_float(~e);
}

#define MFMA(a, b, c) __builtin_amdgcn_mfma_f32_16x16x32_bf16((a), (b), (c), 0, 0, 0)

// P (NORM folded) -> bf16 hi/lo planes in FRAGMENT-MAJOR layout:
//   P2[(d>>3)*256*8 + j*8 + (d&7)]
// so a lane's v8s fragment (j, dslice=q*8+ks*32) is 16 contiguous bytes.
// P2 is 64 KB/plane -> L2-resident; fragments are read per-chunk from L2
// instead of staged in LDS (staging capped residency at 1 block/CU).
__global__ void prep_kernel(const float* __restrict__ proj,
                            ushort* __restrict__ P2hi, ushort* __restrict__ P2lo) {
  int i = blockIdx.x * 256 + threadIdx.x;
  if (i < NFEAT * DHEAD) {
    int j = i >> 6, d = i & 63;
    float x = NORM_C * proj[i];
    ushort h = bf16h(x);
    int off = ((d >> 3) * NFEAT + j) * 8 + (d & 7);
    P2hi[off] = h;
    P2lo[off] = bf16h(x - bf16f(h));
  }
}

// ---------------------------------------------------------------------------
// kmax: global max of dd_k via MFMA. 512 blocks x 512 thr, ~0 LDS,
// 2 blocks/CU. 8 waves = 2 row-halves x 4 j-quarters. 8 chunks of 32 rows.
// ---------------------------------------------------------------------------
__global__ __launch_bounds__(512, 4) void kmax_kernel(
    const float* __restrict__ kk, const ushort* __restrict__ P2hi,
    const ushort* __restrict__ P2lo, unsigned* __restrict__ kmax_u) {
  __shared__ float wred[8];
  const int t = threadIdx.x, lane = t & 63, w = t >> 6;
  const int cl = lane & 15, q = lane >> 4;
  const int mw = w & 1, jq = w >> 1;
  const int head = blockIdx.x >> 4, slab = blockIdx.x & 15;
  const ushort* ph0 = P2hi + (size_t)(q * NFEAT + jq * 64 + cl) * 8;
  const ushort* ph1 = ph0 + (size_t)4 * NFEAT * 8;
  const ushort* pl0 = P2lo + (size_t)(q * NFEAT + jq * 64 + cl) * 8;
  const ushort* pl1 = pl0 + (size_t)4 * NFEAT * 8;
  const float* abase =
      kk + ((size_t)(head * NSEQ + slab * 256 + mw * 16 + cl)) * DHEAD + q * 8;
  float4 pa0 = *(const float4*)(abase);
  float4 pa1 = *(const float4*)(abase + 4);
  float4 pa2 = *(const float4*)(abase + 32);
  float4 pa3 = *(const float4*)(abase + 36);
  float mx = -3.0e38f;
  for (int c = 0; c < 8; ++c) {
    // keep P-frag loads inside the loop (prevent LICM -> 64-VGPR hoist+spill)
    asm volatile("" : "+v"(ph0), "+v"(ph1), "+v"(pl0), "+v"(pl1));
    float af[2][8] = {{pa0.x, pa0.y, pa0.z, pa0.w, pa1.x, pa1.y, pa1.z, pa1.w},
                      {pa2.x, pa2.y, pa2.z, pa2.w, pa3.x, pa3.y, pa3.z, pa3.w}};
    Frag8 ah[2], al[2];
#pragma unroll
    for (int ks = 0; ks < 2; ++ks)
#pragma unroll
      for (int i = 0; i < 8; ++i) {
        ushort h = bf16h(af[ks][i]);
        ah[ks].u[i] = h;
        al[ks].u[i] = bf16h(af[ks][i] - bf16f(h));
      }
    if (c < 7) {
      const float* nx = abase + (size_t)(c + 1) * 32 * DHEAD;
      pa0 = *(const float4*)(nx);
      pa1 = *(const float4*)(nx + 4);
      pa2 = *(const float4*)(nx + 32);
      pa3 = *(const float4*)(nx + 36);
    }
    v4f acc[4];
#pragma unroll
    for (int jt = 0; jt < 4; ++jt) acc[jt] = (v4f){0.f, 0.f, 0.f, 0.f};
#pragma unroll
    for (int ks = 0; ks < 2; ++ks) {
      const ushort* bhp = ks ? ph1 : ph0;
      const ushort* blp = ks ? pl1 : pl0;
#pragma unroll
      for (int jt = 0; jt < 4; ++jt) {
        v8s bh = *(const v8s*)(bhp + jt * 128);
        v8s bl = *(const v8s*)(blp + jt * 128);
        acc[jt] = MFMA(ah[ks].v, bh, acc[jt]);
        acc[jt] = MFMA(ah[ks].v, bl, acc[jt]);
        acc[jt] = MFMA(al[ks].v, bh, acc[jt]);
      }
    }
#pragma unroll
    for (int jt = 0; jt < 4; ++jt)
#pragma unroll
      for (int r = 0; r < 4; ++r) mx = fmaxf(mx, acc[jt][r]);
  }
  for (int s = 1; s < 64; s <<= 1) mx = fmaxf(mx, __shfl_xor(mx, s));
  if (lane == 0) wred[w] = mx;
  __syncthreads();
  if (t == 0) {
    float r = wred[0];
#pragma unroll
    for (int i = 1; i < 8; ++i) r = fmaxf(r, wred[i]);
    atomicMax(kmax_u, enc_f(r));
  }
}

// ---------------------------------------------------------------------------
// kctx: dd_k -> kp (exp) -> LDS -> ctx += kp^T * v, ksum += kp.
// 512 blocks x 512 thr, LDS 50.1 KB -> 2 blocks/CU. 8 chunks of 32 rows.
// Phase-1 waves: (mw = w&1 row-half, jq = w>>1 j-quarter).
// Phase-3 waves: (eh = w&1 e-half, jq3 = w>>1 j-quarter).
// ---------------------------------------------------------------------------
#define KPS 40
#define VTS 40
__global__ __launch_bounds__(512, 4) void kctx_kernel(
    const float* __restrict__ kk, const float* __restrict__ vv,
    const ushort* __restrict__ P2hi, const ushort* __restrict__ P2lo,
    const unsigned* __restrict__ kmax_u, float* __restrict__ ksum,
    float* __restrict__ ctx) {
  __shared__ __align__(16) ushort kphi[NFEAT * KPS];  // 20 KB [j][n]
  __shared__ __align__(16) ushort kplo[NFEAT * KPS];  // 20 KB
  __shared__ __align__(16) ushort vthi[DHEAD * VTS];  // 5 KB  [e][n]
  __shared__ __align__(16) ushort vtlo[DHEAD * VTS];  // 5 KB
  __shared__ float diag[32];
  const int t = threadIdx.x, lane = t & 63, w = t >> 6;
  const int cl = lane & 15, q = lane >> 4;
  const int mw = w & 1, jq = w >> 1;
  const int head = blockIdx.x >> 4, slab = blockIdx.x & 15;
  const float m = dec_f(*kmax_u);
  const ushort* ph0 = P2hi + (size_t)(q * NFEAT + jq * 64 + cl) * 8;
  const ushort* ph1 = ph0 + (size_t)4 * NFEAT * 8;
  const ushort* pl0 = P2lo + (size_t)(q * NFEAT + jq * 64 + cl) * 8;
  const ushort* pl1 = pl0 + (size_t)4 * NFEAT * 8;
  float ksacc[4] = {0.f, 0.f, 0.f, 0.f};
  v4f ctxacc[4][2];
#pragma unroll
  for (int jj = 0; jj < 4; ++jj)
#pragma unroll
    for (int et = 0; et < 2; ++et) ctxacc[jj][et] = (v4f){0.f, 0.f, 0.f, 0.f};

  const float* abase =
      kk + ((size_t)(head * NSEQ + slab * 256 + mw * 16 + cl)) * DHEAD + q * 8;
  const int vrow = t >> 4, ve0 = (t & 15) * 4;
  const float* vbase =
      vv + ((size_t)(head * NSEQ + slab * 256 + vrow)) * DHEAD + ve0;
  float4 pa0 = *(const float4*)(abase);
  float4 pa1 = *(const float4*)(abase + 4);
  float4 pa2 = *(const float4*)(abase + 32);
  float4 pa3 = *(const float4*)(abase + 36);
  float4 pv0 = *(const float4*)(vbase);

  for (int c = 0; c < 8; ++c) {
    __syncthreads();  // prev phase3 done with kp/vt
    asm volatile("" : "+v"(ph0), "+v"(ph1), "+v"(pl0), "+v"(pl1));
    {  // stage v^T bf16 hi/lo [e][n]
      float fv[4] = {pv0.x, pv0.y, pv0.z, pv0.w};
#pragma unroll
      for (int cc = 0; cc < 4; ++cc) {
        int e = ve0 + cc;
        ushort h = bf16h(fv[cc]);
        vthi[e * VTS + vrow] = h;
        vtlo[e * VTS + vrow] = bf16h(fv[cc] - bf16f(h));
      }
    }
    float af[2][8] = {{pa0.x, pa0.y, pa0.z, pa0.w, pa1.x, pa1.y, pa1.z, pa1.w},
                      {pa2.x, pa2.y, pa2.z, pa2.w, pa3.x, pa3.y, pa3.z, pa3.w}};
    Frag8 ah[2], al[2];
    float ssq = 0.f;
#pragma unroll
    for (int ks = 0; ks < 2; ++ks)
#pragma unroll
      for (int i = 0; i < 8; ++i) {
        float x = af[ks][i];
        ssq = fmaf(x, x, ssq);
        ushort h = bf16h(x);
        ah[ks].u[i] = h;
        al[ks].u[i] = bf16h(x - bf16f(h));
      }
    if (c < 7) {  // prefetch next chunk
      const float* nx = abase + (size_t)(c + 1) * 32 * DHEAD;
      pa0 = *(const float4*)(nx);
      pa1 = *(const float4*)(nx + 4);
      pa2 = *(const float4*)(nx + 32);
      pa3 = *(const float4*)(nx + 36);
      pv0 = *(const float4*)(vbase + (size_t)(c + 1) * 32 * DHEAD);
    }
    // phase 1: dd_k (rows mw*16+*, j-quarter jq); P frags from L2
    v4f acc[4];
#pragma unroll
    for (int jt = 0; jt < 4; ++jt) acc[jt] = (v4f){0.f, 0.f, 0.f, 0.f};
#pragma unroll
    for (int ks = 0; ks < 2; ++ks) {
      const ushort* bhp = ks ? ph1 : ph0;
      const ushort* blp = ks ? pl1 : pl0;
#pragma unroll
      for (int jt = 0; jt < 4; ++jt) {
        v8s bh = *(const v8s*)(bhp + jt * 128);
        v8s bl = *(const v8s*)(blp + jt * 128);
        acc[jt] = MFMA(ah[ks].v, bh, acc[jt]);
        acc[jt] = MFMA(ah[ks].v, bl, acc[jt]);
        acc[jt] = MFMA(al[ks].v, bh, acc[jt]);
      }
    }
    {
      float s2 = ssq;
      s2 += __shfl_xor(s2, 16);
      s2 += __shfl_xor(s2, 32);
      if (jq == 0 && q == 0) diag[mw * 16 + cl] = DIAG_C * s2;
    }
    __syncthreads();
    // phase 2: kp = RATIO*(exp(dd - diag - m) + eps) -> bf16 planes [j][n]
#pragma unroll
    for (int jt = 0; jt < 4; ++jt) {
      int j = jq * 64 + jt * 16 + cl;
      float kv[4];
#pragma unroll
      for (int r = 0; r < 4; ++r) {
        int row = mw * 16 + q * 4 + r;
        float e_ = RATIO_C * (__expf(acc[jt][r] - diag[row] - m) + KEPS_C);
        kv[r] = e_;
        ksacc[jt] += e_;
      }
#pragma unroll
      for (int p = 0; p < 2; ++p) {
        ushort h0 = bf16h(kv[2 * p]), h1 = bf16h(kv[2 * p + 1]);
        ushort l0 = bf16h(kv[2 * p] - bf16f(h0));
        ushort l1 = bf16h(kv[2 * p + 1] - bf16f(h1));
        int ui = j * KPS + mw * 16 + q * 4 + 2 * p;
        *(uint*)&kphi[ui] = (uint)h0 | ((uint)h1 << 16);
        *(uint*)&kplo[ui] = (uint)l0 | ((uint)l1 << 16);
      }
    }
    __syncthreads();
    // phase 3: ctx[j][e] += kp^T * v (wave: e-half eh, j-quarter jq3)
    const int eh = w & 1, jq3 = w >> 1;
    v8s bhv[2], blv[2];
#pragma unroll
    for (int et = 0; et < 2; ++et) {
      int e = (eh * 2 + et) * 16 + cl;
      bhv[et] = *(const v8s*)&vthi[e * VTS + q * 8];
      blv[et] = *(const v8s*)&vtlo[e * VTS + q * 8];
    }
#pragma unroll
    for (int jj = 0; jj < 4; ++jj) {
      int jrow = jq3 * 64 + jj * 16 + cl;
      v8s ah2 = *(const v8s*)&kphi[jrow * KPS + q * 8];
      v8s al2 = *(const v8s*)&kplo[jrow * KPS + q * 8];
#pragma unroll
      for (int et = 0; et < 2; ++et) {
        ctxacc[jj][et] = MFMA(ah2, bhv[et], ctxacc[jj][et]);
        ctxacc[jj][et] = MFMA(ah2, blv[et], ctxacc[jj][et]);
        ctxacc[jj][et] = MFMA(al2, bhv[et], ctxacc[jj][et]);
      }
    }
  }
#pragma unroll
  for (int jt = 0; jt < 4; ++jt) {
    float s = ksacc[jt];
    s += __shfl_xor(s, 16);
    s += __shfl_xor(s, 32);
    if (q == 0) atomicAdd(&ksum[head * NFEAT + jq * 64 + jt * 16 + cl], s);
  }
  {
    const int eh = w & 1, jq3 = w >> 1;
#pragma unroll
    for (int jj = 0; jj < 4; ++jj)
#pragma unroll
      for (int et = 0; et < 2; ++et)
#pragma unroll
        for (int r = 0; r < 4; ++r) {
          int j = jq3 * 64 + jj * 16 + q * 4 + r;
          int e = (eh * 2 + et) * 16 + cl;
          atomicAdd(&ctx[((size_t)head * NFEAT + j) * DHEAD + e],
                    ctxacc[jj][et][r]);
        }
  }
}

// ---------------------------------------------------------------------------
// ctxprep: ctx fp32 [h][j][e] -> ctxT bf16 hi/lo planes [h][e][j]
// ---------------------------------------------------------------------------
__global__ void ctxprep_kernel(const float* __restrict__ ctx,
                               ushort* __restrict__ ctxThi,
                               ushort* __restrict__ ctxTlo) {
  __shared__ float tile[64 * 65];
  const int head = blockIdx.x >> 2, jb = blockIdx.x & 3, t = threadIdx.x;
#pragma unroll
  for (int i = 0; i < 16; ++i) {
    int idx = t + i * 256;
    int jj = idx >> 6, e = idx & 63;
    tile[jj * 65 + e] = ctx[((size_t)head * NFEAT + jb * 64 + jj) * DHEAD + e];
  }
  __syncthreads();
#pragma unroll
  for (int i = 0; i < 16; ++i) {
    int idx = t + i * 256;
    int e = idx >> 6, jj = idx & 63;
    float x = tile[jj * 65 + e];
    ushort h = bf16h(x);
    size_t o = ((size_t)head * DHEAD + e) * NFEAT + jb * 64 + jj;
    ctxThi[o] = h;
    ctxTlo[o] = bf16h(x - bf16f(h));
  }
}

// ---------------------------------------------------------------------------
// qout: dd_q -> rowmax -> qp -> LDS; d_inv; out = (qp . ctxT) * d_inv.
// 512 blocks x 512 thr, LDS 43.6 KB -> 2 blocks/CU. 8 chunks of 32 rows.
// P and ctxT fragments read per-chunk from L2 (both are L2-resident and
// chunk-invariant); ctxT loads issued right after the phase-1 barrier so
// their latency hides under phase-2's exp work.
// ---------------------------------------------------------------------------
#define QPS 264
#define OS 68
__global__ __launch_bounds__(512, 4) void qout_kernel(
    const float* __restrict__ qq, const ushort* __restrict__ P2hi,
    const ushort* __restrict__ P2lo, const float* __restrict__ ksum,
    const ushort* __restrict__ ctxThi, const ushort* __restrict__ ctxTlo,
    float* __restrict__ out) {
  __shared__ __align__(16) ushort qphi[32 * QPS];  // 16.5 KB [n][j]
  __shared__ __align__(16) ushort qplo[32 * QPS];
  __shared__ __align__(16) float souts[32 * OS];   // 8.5 KB
  __shared__ float diag[32];
  __shared__ float mpart[4][32], dpart[4][32];
  const int t = threadIdx.x, lane = t & 63, w = t >> 6;
  const int cl = lane & 15, q = lane >> 4;
  const int mw = w & 1, jq = w >> 1;     // phase-1 mapping
  const int mw3 = w & 1, et3 = w >> 1;   // phase-3 mapping
  const int head = blockIdx.x >> 4, slab = blockIdx.x & 15;
  const ushort* ph0 = P2hi + (size_t)(q * NFEAT + jq * 64 + cl) * 8;
  const ushort* ph1 = ph0 + (size_t)4 * NFEAT * 8;
  const ushort* pl0 = P2lo + (size_t)(q * NFEAT + jq * 64 + cl) * 8;
  const ushort* pl1 = pl0 + (size_t)4 * NFEAT * 8;
  const ushort* cbh =
      ctxThi + ((size_t)head * DHEAD + et3 * 16 + cl) * NFEAT + q * 8;
  const ushort* cbl =
      ctxTlo + ((size_t)head * DHEAD + et3 * 16 + cl) * NFEAT + q * 8;
  float ksl[4];
#pragma unroll
  for (int jt = 0; jt < 4; ++jt)
    ksl[jt] = ksum[head * NFEAT + jq * 64 + jt * 16 + cl];
  const float* abase =
      qq + ((size_t)(head * NSEQ + slab * 256 + mw * 16 + cl)) * DHEAD + q * 8;
  float4 pa0 = *(const float4*)(abase);
  float4 pa1 = *(const float4*)(abase + 4);
  float4 pa2 = *(const float4*)(abase + 32);
  float4 pa3 = *(const float4*)(abase + 36);

  for (int c = 0; c < 8; ++c) {
    const int row0 = slab * 256 + c * 32;
    asm volatile("" : "+v"(ph0), "+v"(ph1), "+v"(pl0), "+v"(pl1),
                      "+v"(cbh), "+v"(cbl));
    float af[2][8] = {{pa0.x, pa0.y, pa0.z, pa0.w, pa1.x, pa1.y, pa1.z, pa1.w},
                      {pa2.x, pa2.y, pa2.z, pa2.w, pa3.x, pa3.y, pa3.z, pa3.w}};
    Frag8 ah[2], al[2];
    float ssq = 0.f;
#pragma unroll
    for (int ks = 0; ks < 2; ++ks)
#pragma unroll
      for (int i = 0; i < 8; ++i) {
        float x = af[ks][i];
        ssq = fmaf(x, x, ssq);
        ushort h = bf16h(x);
        ah[ks].u[i] = h;
        al[ks].u[i] = bf16h(x - bf16f(h));
      }
    if (c < 7) {
      const float* nx = abase + (size_t)(c + 1) * 32 * DHEAD;
      pa0 = *(const float4*)(nx);
      pa1 = *(const float4*)(nx + 4);
      pa2 = *(const float4*)(nx + 32);
      pa3 = *(const float4*)(nx + 36);
    }
    // phase 1: dd_q (rows mw*16+*, j-quarter jq); P frags from L2
    v4f acc[4];
#pragma unroll
    for (int jt = 0; jt < 4; ++jt) acc[jt] = (v4f){0.f, 0.f, 0.f, 0.f};
#pragma unroll
    for (int ks = 0; ks < 2; ++ks) {
      const ushort* bhp = ks ? ph1 : ph0;
      const ushort* blp = ks ? pl1 : pl0;
#pragma unroll
      for (int jt = 0; jt < 4; ++jt) {
        v8s bh = *(const v8s*)(bhp + jt * 128);
        v8s bl = *(const v8s*)(blp + jt * 128);
        acc[jt] = MFMA(ah[ks].v, bh, acc[jt]);
        acc[jt] = MFMA(ah[ks].v, bl, acc[jt]);
        acc[jt] = MFMA(al[ks].v, bh, acc[jt]);
      }
    }
    {
      float s2 = ssq;
      s2 += __shfl_xor(s2, 16);
      s2 += __shfl_xor(s2, 32);
      if (jq == 0 && q == 0) diag[mw * 16 + cl] = DIAG_C * s2;
    }
    // per-row max over this wave's j-quarter
#pragma unroll
    for (int r = 0; r < 4; ++r) {
      float mr = acc[0][r];
#pragma unroll
      for (int jt = 1; jt < 4; ++jt) mr = fmaxf(mr, acc[jt][r]);
      mr = fmaxf(mr, __shfl_xor(mr, 1));
      mr = fmaxf(mr, __shfl_xor(mr, 2));
      mr = fmaxf(mr, __shfl_xor(mr, 4));
      mr = fmaxf(mr, __shfl_xor(mr, 8));
      if (cl == 0) mpart[jq][mw * 16 + q * 4 + r] = mr;
    }
    __syncthreads();
    // issue ctxT B-fragment loads (L2) early; consumed in phase 3
    v8s bhr[8], blr[8];
#pragma unroll
    for (int ks8 = 0; ks8 < 8; ++ks8) {
      bhr[ks8] = *(const v8s*)(cbh + ks8 * 32);
      blr[ks8] = *(const v8s*)(cbl + ks8 * 32);
    }
    // phase 2: exp, qp store, d-partials
#pragma unroll
    for (int r = 0; r < 4; ++r) {
      int row = mw * 16 + q * 4 + r;
      float mm = fmaxf(fmaxf(mpart[0][row], mpart[1][row]),
                       fmaxf(mpart[2][row], mpart[3][row])) + diag[row];
      float ds = 0.f;
#pragma unroll
      for (int jt = 0; jt < 4; ++jt) {
        float qv = RATIO_C * (__expf(acc[jt][r] - mm) + KEPS_C);
        ds = fmaf(qv, ksl[jt], ds);
        int j = jq * 64 + jt * 16 + cl;
        ushort h = bf16h(qv);
        qphi[row * QPS + j] = h;
        qplo[row * QPS + j] = bf16h(qv - bf16f(h));
      }
      ds += __shfl_xor(ds, 1);
      ds += __shfl_xor(ds, 2);
      ds += __shfl_xor(ds, 4);
      ds += __shfl_xor(ds, 8);
      if (cl == 0) dpart[jq][row] = ds;
    }
    __syncthreads();
    // phase 3: (m,e)-tile GEMM, K=256, two accumulator chains
    v4f oaccA = (v4f){0.f, 0.f, 0.f, 0.f};
    v4f oaccB = (v4f){0.f, 0.f, 0.f, 0.f};
#pragma unroll
    for (int ks8 = 0; ks8 < 8; ks8 += 2) {
      v8s ahq0 = *(const v8s*)&qphi[(mw3 * 16 + cl) * QPS + ks8 * 32 + q * 8];
      v8s alq0 = *(const v8s*)&qplo[(mw3 * 16 + cl) * QPS + ks8 * 32 + q * 8];
      v8s ahq1 =
          *(const v8s*)&qphi[(mw3 * 16 + cl) * QPS + (ks8 + 1) * 32 + q * 8];
      v8s alq1 =
          *(const v8s*)&qplo[(mw3 * 16 + cl) * QPS + (ks8 + 1) * 32 + q * 8];
      oaccA = MFMA(ahq0, bhr[ks8], oaccA);
      oaccA = MFMA(ahq0, blr[ks8], oaccA);
      oaccA = MFMA(alq0, bhr[ks8], oaccA);
      oaccB = MFMA(ahq1, bhr[ks8 + 1], oaccB);
      oaccB = MFMA(ahq1, blr[ks8 + 1], oaccB);
      oaccB = MFMA(alq1, bhr[ks8 + 1], oaccB);
    }
#pragma unroll
    for (int r = 0; r < 4; ++r) {
      int row = mw3 * 16 + q * 4 + r;
      float di = 1.0f / (dpart[0][row] + dpart[1][row] + dpart[2][row] +
                         dpart[3][row]);
      souts[row * OS + et3 * 16 + cl] = (oaccA[r] + oaccB[r]) * di;
    }
    __syncthreads();
    {  // coalesced 32x64 tile store
      const int row = t >> 4, eo = (t & 15) * 4;
      float4 rr = *(const float4*)&souts[row * OS + eo];
      *(float4*)(out + ((size_t)(head * NSEQ + row0 + row)) * DHEAD + eo) = rr;
    }
    __syncthreads();  // souts/qp consumed before next chunk overwrites
  }
}

extern "C" void kernel_launch(void* const* d_in, const int* in_sizes, int n_in,
                              void* d_out, int out_size, void* d_ws, size_t ws_size,
                              hipStream_t stream) {
  (void)in_sizes; (void)n_in; (void)out_size; (void)ws_size;
  const float* q = (const float*)d_in[0];
  const float* k = (const float*)d_in[1];
  const float* v = (const float*)d_in[2];
  const float* proj = (const float*)d_in[3];
  float* out = (float*)d_out;
  unsigned char* ws = (unsigned char*)d_ws;
  unsigned* kmax_u = (unsigned*)ws;                    // @0
  float* ksum = (float*)(ws + 256);                    // 32 KB
  float* ctx = (float*)(ws + 33024);                   // 2 MB
  ushort* P2hi = (ushort*)(ws + 2130176);              // 32 KB
  ushort* P2lo = (ushort*)(ws + 2162944);              // 32 KB
  ushort* ctxThi = (ushort*)(ws + 2195712);            // 1 MB
  ushort* ctxTlo = (ushort*)(ws + 3244288);            // 1 MB -> end 4292864
  hipMemsetAsync(d_ws, 0, 2130176, stream);  // kmax_u + ksum + ctx
  hipLaunchKernelGGL(prep_kernel, dim3(64), dim3(256), 0, stream, proj, P2hi, P2lo);
  hipLaunchKernelGGL(kmax_kernel, dim3(512), dim3(512), 0, stream, k, P2hi, P2lo,
                     kmax_u);
  hipLaunchKernelGGL(kctx_kernel, dim3(512), dim3(512), 0, stream, k, v, P2hi,
                     P2lo, kmax_u, ksum, ctx);
  hipLaunchKernelGGL(ctxprep_kernel, dim3(128), dim3(256), 0, stream, ctx,
                     ctxThi, ctxTlo);
  hipLaunchKernelGGL(qout_kernel, dim3(512), dim3(512), 0, stream, q, P2hi,
                     P2lo, ksum, ctxThi, ctxTlo, out);
}

// Round 2
// 304.560 us; speedup vs baseline: 1.1723x; 1.1723x over previous
//
#include <hip/hip_runtime.h>

#define NFEAT 256
#define DHEAD 64
#define NSEQ  4096

constexpr float NORM_C  = 0.35355339059327373f;  // 64^-0.25
constexpr float RATIO_C = 0.0625f;               // 256^-0.5
constexpr float DIAG_C  = 0.0625f;               // 0.5 * 64^-0.5
constexpr float KEPS_C  = 1e-4f;

using v8s = __attribute__((ext_vector_type(8))) short;
using v4f = __attribute__((ext_vector_type(4))) float;
union Frag8 { v8s v; ushort u[8]; };

__device__ __forceinline__ ushort bf16h(float x) {
  unsigned u = __float_as_uint(x);
  return (ushort)((u + 0x7FFFu + ((u >> 16) & 1)) >> 16);
}
__device__ __forceinline__ float bf16f(ushort h) {
  return __uint_as_float(((unsigned)h) << 16);
}
__device__ __forceinline__ unsigned enc_f(float f) {
  unsigned u = __float_as_uint(f);
  return (u & 0x80000000u) ? ~u : (u | 0x80000000u);
}
__device__ __forceinline__ float dec_f(unsigned e) {
  return (e & 0x80000000u) ? __uint_as_float(e ^ 0x80000000u) : __uint_as_float(~e);
}

#define MFMA(a, b, c) __builtin_amdgcn_mfma_f32_16x16x32_bf16((a), (b), (c), 0, 0, 0)

// P (NORM folded) -> bf16 hi/lo planes in FRAGMENT-MAJOR layout:
//   P2[(d>>3)*256*8 + j*8 + (d&7)]
// so a lane's v8s fragment (j, dslice=q*8+ks*32) is 16 contiguous bytes.
// hi plane is staged per-block into LDS (hot operand); lo plane is read
// transiently from L2 (16 VGPRs in flight, paced by pointer clobbers).
__global__ void prep_kernel(const float* __restrict__ proj,
                            ushort* __restrict__ P2hi, ushort* __restrict__ P2lo) {
  int i = blockIdx.x * 256 + threadIdx.x;
  if (i < NFEAT * DHEAD) {
    int j = i >> 6, d = i & 63;
    float x = NORM_C * proj[i];
    ushort h = bf16h(x);
    int off = ((d >> 3) * NFEAT + j) * 8 + (d & 7);
    P2hi[off] = h;
    P2lo[off] = bf16h(x - bf16f(h));
  }
}

// ---------------------------------------------------------------------------
// kmax: global max of dd_k via MFMA, SINGLE bf16 plane (m only needs ~1e-2
// accuracy: it cancels in out up to eps*delta). 512 blocks x 512 thr,
// LDS 32 KB, launch_bounds(512,4) -> 2 blocks/CU. 8 chunks of 32 rows.
// ---------------------------------------------------------------------------
__global__ __launch_bounds__(512, 4) void kmax_kernel(
    const float* __restrict__ kk, const ushort* __restrict__ P2hi,
    unsigned* __restrict__ kmax_u) {
  __shared__ __align__(16) ushort PhiL[NFEAT * DHEAD];  // 32 KB
  __shared__ float wred[8];
  const int t = threadIdx.x, lane = t & 63, w = t >> 6;
  const int cl = lane & 15, q = lane >> 4;
  const int mw = w & 1, jq = w >> 1;
  const int head = blockIdx.x >> 4, slab = blockIdx.x & 15;
  for (int i = t; i < 2048; i += 512)
    ((float4*)PhiL)[i] = ((const float4*)P2hi)[i];
  const float* abase =
      kk + ((size_t)(head * NSEQ + slab * 256 + mw * 16 + cl)) * DHEAD + q * 8;
  float4 pa0 = *(const float4*)(abase);
  float4 pa1 = *(const float4*)(abase + 4);
  float4 pa2 = *(const float4*)(abase + 32);
  float4 pa3 = *(const float4*)(abase + 36);
  __syncthreads();
  float mx = -3.0e38f;
  for (int c = 0; c < 8; ++c) {
    float af[2][8] = {{pa0.x, pa0.y, pa0.z, pa0.w, pa1.x, pa1.y, pa1.z, pa1.w},
                      {pa2.x, pa2.y, pa2.z, pa2.w, pa3.x, pa3.y, pa3.z, pa3.w}};
    Frag8 ah[2];
#pragma unroll
    for (int ks = 0; ks < 2; ++ks)
#pragma unroll
      for (int i = 0; i < 8; ++i) ah[ks].u[i] = bf16h(af[ks][i]);
    if (c < 7) {
      const float* nx = abase + (size_t)(c + 1) * 32 * DHEAD;
      pa0 = *(const float4*)(nx);
      pa1 = *(const float4*)(nx + 4);
      pa2 = *(const float4*)(nx + 32);
      pa3 = *(const float4*)(nx + 36);
    }
    v4f acc[4];
#pragma unroll
    for (int jt = 0; jt < 4; ++jt) acc[jt] = (v4f){0.f, 0.f, 0.f, 0.f};
#pragma unroll
    for (int ks = 0; ks < 2; ++ks)
#pragma unroll
      for (int jt = 0; jt < 4; ++jt) {
        v8s bh = *(const v8s*)&PhiL[((ks * 4 + q) * NFEAT + jq * 64 + jt * 16 + cl) * 8];
        acc[jt] = MFMA(ah[ks].v, bh, acc[jt]);
      }
#pragma unroll
    for (int jt = 0; jt < 4; ++jt)
#pragma unroll
      for (int r = 0; r < 4; ++r) mx = fmaxf(mx, acc[jt][r]);
  }
  for (int s = 1; s < 64; s <<= 1) mx = fmaxf(mx, __shfl_xor(mx, s));
  if (lane == 0) wred[w] = mx;
  __syncthreads();
  if (t == 0) {
    float r = wred[0];
#pragma unroll
    for (int i = 1; i < 8; ++i) r = fmaxf(r, wred[i]);
    atomicMax(kmax_u, enc_f(r));
  }
}

// ---------------------------------------------------------------------------
// kctx: dd_k -> kp (exp) -> LDS -> ctx += kp^T * v, ksum += kp.
// 512 blocks x 512 thr, LDS = 32K (P-hi) + 40K (kp) = 73.7 KB -> 2 blocks/CU.
// P-lo from L2 transient; V fragments loaded directly from global in phase 3
// (chunk is 8 KB, warmed by a 1-float4/thread prefetch); diag via shfl
// (no LDS, no phase1->2 barrier). 8 chunks of 32 rows, 2 barriers/chunk.
// ---------------------------------------------------------------------------
#define KPS 40
__global__ __launch_bounds__(512, 4) void kctx_kernel(
    const float* __restrict__ kk, const float* __restrict__ vv,
    const ushort* __restrict__ P2hi, const ushort* __restrict__ P2lo,
    const unsigned* __restrict__ kmax_u, float* __restrict__ ksum,
    float* __restrict__ ctx) {
  __shared__ __align__(16) ushort PhiL[NFEAT * DHEAD];  // 32 KB
  __shared__ __align__(16) ushort kphi[NFEAT * KPS];    // 20 KB [j][n]
  __shared__ __align__(16) ushort kplo[NFEAT * KPS];    // 20 KB
  const int t = threadIdx.x, lane = t & 63, w = t >> 6;
  const int cl = lane & 15, q = lane >> 4;
  const int mw = w & 1, jq = w >> 1;
  const int head = blockIdx.x >> 4, slab = blockIdx.x & 15;
  const float m = dec_f(*kmax_u);
  const ushort* pl0 = P2lo + (size_t)(q * NFEAT + jq * 64 + cl) * 8;
  const ushort* pl1 = pl0 + (size_t)4 * NFEAT * 8;
  for (int i = t; i < 2048; i += 512)
    ((float4*)PhiL)[i] = ((const float4*)P2hi)[i];
  float ksacc[4] = {0.f, 0.f, 0.f, 0.f};
  v4f ctxacc[4][2];
#pragma unroll
  for (int jj = 0; jj < 4; ++jj)
#pragma unroll
    for (int et = 0; et < 2; ++et) ctxacc[jj][et] = (v4f){0.f, 0.f, 0.f, 0.f};

  const float* abase =
      kk + ((size_t)(head * NSEQ + slab * 256 + mw * 16 + cl)) * DHEAD + q * 8;
  const float* vwarm =
      vv + ((size_t)(head * NSEQ + slab * 256 + (t >> 4))) * DHEAD + (t & 15) * 4;
  float4 pa0 = *(const float4*)(abase);
  float4 pa1 = *(const float4*)(abase + 4);
  float4 pa2 = *(const float4*)(abase + 32);
  float4 pa3 = *(const float4*)(abase + 36);
  {  // warm chunk-0 V into L1/L2
    float4 wv = *(const float4*)(vwarm);
    asm volatile("" :: "v"(wv.x), "v"(wv.y), "v"(wv.z), "v"(wv.w));
  }
  __syncthreads();  // PhiL staged

  for (int c = 0; c < 8; ++c) {
    if (c) __syncthreads();  // prev phase3 done reading kp
    float af[2][8] = {{pa0.x, pa0.y, pa0.z, pa0.w, pa1.x, pa1.y, pa1.z, pa1.w},
                      {pa2.x, pa2.y, pa2.z, pa2.w, pa3.x, pa3.y, pa3.z, pa3.w}};
    Frag8 ah[2], al[2];
    float ssq = 0.f;
#pragma unroll
    for (int ks = 0; ks < 2; ++ks)
#pragma unroll
      for (int i = 0; i < 8; ++i) {
        float x = af[ks][i];
        ssq = fmaf(x, x, ssq);
        ushort h = bf16h(x);
        ah[ks].u[i] = h;
        al[ks].u[i] = bf16h(x - bf16f(h));
      }
    if (c < 7) {  // prefetch next K chunk + warm next V chunk
      const float* nx = abase + (size_t)(c + 1) * 32 * DHEAD;
      pa0 = *(const float4*)(nx);
      pa1 = *(const float4*)(nx + 4);
      pa2 = *(const float4*)(nx + 32);
      pa3 = *(const float4*)(nx + 36);
      float4 wv = *(const float4*)(vwarm + (size_t)(c + 1) * 32 * DHEAD);
      asm volatile("" :: "v"(wv.x), "v"(wv.y), "v"(wv.z), "v"(wv.w));
    }
    // phase 1: dd_k (rows mw*16+*, j-quarter jq); P-hi LDS, P-lo L2 paced
    v4f acc[4];
#pragma unroll
    for (int jt = 0; jt < 4; ++jt) acc[jt] = (v4f){0.f, 0.f, 0.f, 0.f};
#pragma unroll
    for (int ks = 0; ks < 2; ++ks) {
      asm volatile("" : "+v"(pl0), "+v"(pl1));
      const ushort* blp = ks ? pl1 : pl0;
      v8s bl[4];
#pragma unroll
      for (int jt = 0; jt < 4; ++jt) bl[jt] = *(const v8s*)(blp + jt * 128);
#pragma unroll
      for (int jt = 0; jt < 4; ++jt) {
        v8s bh = *(const v8s*)&PhiL[((ks * 4 + q) * NFEAT + jq * 64 + jt * 16 + cl) * 8];
        acc[jt] = MFMA(ah[ks].v, bh, acc[jt]);
        acc[jt] = MFMA(ah[ks].v, bl[jt], acc[jt]);
        acc[jt] = MFMA(al[ks].v, bh, acc[jt]);
      }
    }
    float s2 = ssq;
    s2 += __shfl_xor(s2, 16);
    s2 += __shfl_xor(s2, 32);
    // s2 = full ssq of row mw*16+cl in every lane
    // phase 2 (no barrier needed: only own acc + shfl'd diag)
    float dg[4];
#pragma unroll
    for (int r = 0; r < 4; ++r) dg[r] = DIAG_C * __shfl(s2, q * 4 + r);
#pragma unroll
    for (int jt = 0; jt < 4; ++jt) {
      int j = jq * 64 + jt * 16 + cl;
      float kv[4];
#pragma unroll
      for (int r = 0; r < 4; ++r) {
        float e_ = RATIO_C * (__expf(acc[jt][r] - dg[r] - m) + KEPS_C);
        kv[r] = e_;
        ksacc[jt] += e_;
      }
#pragma unroll
      for (int p = 0; p < 2; ++p) {
        ushort h0 = bf16h(kv[2 * p]), h1 = bf16h(kv[2 * p + 1]);
        ushort l0 = bf16h(kv[2 * p] - bf16f(h0));
        ushort l1 = bf16h(kv[2 * p + 1] - bf16f(h1));
        int ui = j * KPS + mw * 16 + q * 4 + 2 * p;
        *(uint*)&kphi[ui] = (uint)h0 | ((uint)h1 << 16);
        *(uint*)&kplo[ui] = (uint)l0 | ((uint)l1 << 16);
      }
    }
    __syncthreads();
    // phase 3: ctx[j][e] += kp^T * v (wave: e-half eh, j-quarter jq3)
    const int eh = w & 1, jq3 = w >> 1;
    Frag8 bhv[2], blv[2];
    {  // V B-fragments straight from global (L1/L2-hit after warm)
      const float* vch =
          vv + ((size_t)(head * NSEQ + slab * 256 + c * 32 + q * 8)) * DHEAD +
          eh * 32 + cl;
#pragma unroll
      for (int et = 0; et < 2; ++et)
#pragma unroll
        for (int i = 0; i < 8; ++i) {
          float x = vch[(size_t)i * DHEAD + et * 16];
          ushort h = bf16h(x);
          bhv[et].u[i] = h;
          blv[et].u[i] = bf16h(x - bf16f(h));
        }
    }
#pragma unroll
    for (int jj = 0; jj < 4; ++jj) {
      int jrow = jq3 * 64 + jj * 16 + cl;
      v8s ah2 = *(const v8s*)&kphi[jrow * KPS + q * 8];
      v8s al2 = *(const v8s*)&kplo[jrow * KPS + q * 8];
#pragma unroll
      for (int et = 0; et < 2; ++et) {
        ctxacc[jj][et] = MFMA(ah2, bhv[et].v, ctxacc[jj][et]);
        ctxacc[jj][et] = MFMA(ah2, blv[et].v, ctxacc[jj][et]);
        ctxacc[jj][et] = MFMA(al2, bhv[et].v, ctxacc[jj][et]);
      }
    }
  }
#pragma unroll
  for (int jt = 0; jt < 4; ++jt) {
    float s = ksacc[jt];
    s += __shfl_xor(s, 16);
    s += __shfl_xor(s, 32);
    if (q == 0) atomicAdd(&ksum[head * NFEAT + jq * 64 + jt * 16 + cl], s);
  }
  {
    const int eh = w & 1, jq3 = w >> 1;
#pragma unroll
    for (int jj = 0; jj < 4; ++jj)
#pragma unroll
      for (int et = 0; et < 2; ++et)
#pragma unroll
        for (int r = 0; r < 4; ++r) {
          int j = jq3 * 64 + jj * 16 + q * 4 + r;
          int e = (eh * 2 + et) * 16 + cl;
          atomicAdd(&ctx[((size_t)head * NFEAT + j) * DHEAD + e],
                    ctxacc[jj][et][r]);
        }
  }
}

// ---------------------------------------------------------------------------
// ctxprep: ctx fp32 [h][j][e] -> ctxT bf16 hi/lo planes [h][e][j]
// ---------------------------------------------------------------------------
__global__ void ctxprep_kernel(const float* __restrict__ ctx,
                               ushort* __restrict__ ctxThi,
                               ushort* __restrict__ ctxTlo) {
  __shared__ float tile[64 * 65];
  const int head = blockIdx.x >> 2, jb = blockIdx.x & 3, t = threadIdx.x;
#pragma unroll
  for (int i = 0; i < 16; ++i) {
    int idx = t + i * 256;
    int jj = idx >> 6, e = idx & 63;
    tile[jj * 65 + e] = ctx[((size_t)head * NFEAT + jb * 64 + jj) * DHEAD + e];
  }
  __syncthreads();
#pragma unroll
  for (int i = 0; i < 16; ++i) {
    int idx = t + i * 256;
    int e = idx >> 6, jj = idx & 63;
    float x = tile[jj * 65 + e];
    ushort h = bf16h(x);
    size_t o = ((size_t)head * DHEAD + e) * NFEAT + jb * 64 + jj;
    ctxThi[o] = h;
    ctxTlo[o] = bf16h(x - bf16f(h));
  }
}

// ---------------------------------------------------------------------------
// qout: dd_q -> rowmax -> qp -> LDS; d_inv; out = (qp . ctxT) * d_inv.
// 512 blocks x 512 thr, LDS = 32K (P-hi) + 33K (qp) + 8.7K (souts) + 1K
// = 75.3 KB -> 2 blocks/CU. P-lo and ctxT fragments from L2, transient and
// paced (no persistent 64-reg array -> no spill). diag via shfl. 8 chunks,
// 3 barriers/chunk.
// ---------------------------------------------------------------------------
#define QPS 264
#define OS 68
__global__ __launch_bounds__(512, 4) void qout_kernel(
    const float* __restrict__ qq, const ushort* __restrict__ P2hi,
    const ushort* __restrict__ P2lo, const float* __restrict__ ksum,
    const ushort* __restrict__ ctxThi, const ushort* __restrict__ ctxTlo,
    float* __restrict__ out) {
  __shared__ __align__(16) ushort PhiL[NFEAT * DHEAD];  // 32 KB
  __shared__ __align__(16) ushort qphi[32 * QPS];       // 16.5 KB [n][j]
  __shared__ __align__(16) ushort qplo[32 * QPS];
  __shared__ __align__(16) float souts[32 * OS];        // 8.5 KB
  __shared__ float mpart[4][32], dpart[4][32];
  const int t = threadIdx.x, lane = t & 63, w = t >> 6;
  const int cl = lane & 15, q = lane >> 4;
  const int mw = w & 1, jq = w >> 1;     // phase-1 mapping
  const int mw3 = w & 1, et3 = w >> 1;   // phase-3 mapping
  const int head = blockIdx.x >> 4, slab = blockIdx.x & 15;
  const ushort* pl0 = P2lo + (size_t)(q * NFEAT + jq * 64 + cl) * 8;
  const ushort* pl1 = pl0 + (size_t)4 * NFEAT * 8;
  const ushort* cbh =
      ctxThi + ((size_t)head * DHEAD + et3 * 16 + cl) * NFEAT + q * 8;
  const ushort* cbl =
      ctxTlo + ((size_t)head * DHEAD + et3 * 16 + cl) * NFEAT + q * 8;
  for (int i = t; i < 2048; i += 512)
    ((float4*)PhiL)[i] = ((const float4*)P2hi)[i];
  float ksl[4];
#pragma unroll
  for (int jt = 0; jt < 4; ++jt)
    ksl[jt] = ksum[head * NFEAT + jq * 64 + jt * 16 + cl];
  const float* abase =
      qq + ((size_t)(head * NSEQ + slab * 256 + mw * 16 + cl)) * DHEAD + q * 8;
  float4 pa0 = *(const float4*)(abase);
  float4 pa1 = *(const float4*)(abase + 4);
  float4 pa2 = *(const float4*)(abase + 32);
  float4 pa3 = *(const float4*)(abase + 36);
  __syncthreads();  // PhiL staged

  for (int c = 0; c < 8; ++c) {
    const int row0 = slab * 256 + c * 32;
    float af[2][8] = {{pa0.x, pa0.y, pa0.z, pa0.w, pa1.x, pa1.y, pa1.z, pa1.w},
                      {pa2.x, pa2.y, pa2.z, pa2.w, pa3.x, pa3.y, pa3.z, pa3.w}};
    Frag8 ah[2], al[2];
    float ssq = 0.f;
#pragma unroll
    for (int ks = 0; ks < 2; ++ks)
#pragma unroll
      for (int i = 0; i < 8; ++i) {
        float x = af[ks][i];
        ssq = fmaf(x, x, ssq);
        ushort h = bf16h(x);
        ah[ks].u[i] = h;
        al[ks].u[i] = bf16h(x - bf16f(h));
      }
    if (c < 7) {
      const float* nx = abase + (size_t)(c + 1) * 32 * DHEAD;
      pa0 = *(const float4*)(nx);
      pa1 = *(const float4*)(nx + 4);
      pa2 = *(const float4*)(nx + 32);
      pa3 = *(const float4*)(nx + 36);
    }
    // phase 1: dd_q; P-hi LDS, P-lo L2 paced
    v4f acc[4];
#pragma unroll
    for (int jt = 0; jt < 4; ++jt) acc[jt] = (v4f){0.f, 0.f, 0.f, 0.f};
#pragma unroll
    for (int ks = 0; ks < 2; ++ks) {
      asm volatile("" : "+v"(pl0), "+v"(pl1));
      const ushort* blp = ks ? pl1 : pl0;
      v8s bl[4];
#pragma unroll
      for (int jt = 0; jt < 4; ++jt) bl[jt] = *(const v8s*)(blp + jt * 128);
#pragma unroll
      for (int jt = 0; jt < 4; ++jt) {
        v8s bh = *(const v8s*)&PhiL[((ks * 4 + q) * NFEAT + jq * 64 + jt * 16 + cl) * 8];
        acc[jt] = MFMA(ah[ks].v, bh, acc[jt]);
        acc[jt] = MFMA(ah[ks].v, bl[jt], acc[jt]);
        acc[jt] = MFMA(al[ks].v, bh, acc[jt]);
      }
    }
    float s2 = ssq;
    s2 += __shfl_xor(s2, 16);
    s2 += __shfl_xor(s2, 32);
    // per-row max over this wave's j-quarter
#pragma unroll
    for (int r = 0; r < 4; ++r) {
      float mr = acc[0][r];
#pragma unroll
      for (int jt = 1; jt < 4; ++jt) mr = fmaxf(mr, acc[jt][r]);
      mr = fmaxf(mr, __shfl_xor(mr, 1));
      mr = fmaxf(mr, __shfl_xor(mr, 2));
      mr = fmaxf(mr, __shfl_xor(mr, 4));
      mr = fmaxf(mr, __shfl_xor(mr, 8));
      if (cl == 0) mpart[jq][mw * 16 + q * 4 + r] = mr;
    }
    __syncthreads();  // (1) mpart ready
    // phase 2: exp, qp store, d-partials (diag via shfl, no LDS)
#pragma unroll
    for (int r = 0; r < 4; ++r) {
      int row = mw * 16 + q * 4 + r;
      float dgr = DIAG_C * __shfl(s2, q * 4 + r);
      float mm = fmaxf(fmaxf(mpart[0][row], mpart[1][row]),
                       fmaxf(mpart[2][row], mpart[3][row])) + dgr;
      float ds = 0.f;
#pragma unroll
      for (int jt = 0; jt < 4; ++jt) {
        float qv = RATIO_C * (__expf(acc[jt][r] - mm) + KEPS_C);
        ds = fmaf(qv, ksl[jt], ds);
        int j = jq * 64 + jt * 16 + cl;
        ushort h = bf16h(qv);
        qphi[row * QPS + j] = h;
        qplo[row * QPS + j] = bf16h(qv - bf16f(h));
      }
      ds += __shfl_xor(ds, 1);
      ds += __shfl_xor(ds, 2);
      ds += __shfl_xor(ds, 4);
      ds += __shfl_xor(ds, 8);
      if (cl == 0) dpart[jq][row] = ds;
    }
    __syncthreads();  // (2) qp/dpart ready
    // phase 3: (m,e)-tile GEMM, K=256; ctxT frags from L2, paced pairs,
    // dual accumulator chains
    v4f oaccA = (v4f){0.f, 0.f, 0.f, 0.f};
    v4f oaccB = (v4f){0.f, 0.f, 0.f, 0.f};
#pragma unroll
    for (int ks8 = 0; ks8 < 8; ks8 += 2) {
      asm volatile("" : "+v"(cbh), "+v"(cbl));
      v8s b0h = *(const v8s*)(cbh + ks8 * 32);
      v8s b0l = *(const v8s*)(cbl + ks8 * 32);
      v8s b1h = *(const v8s*)(cbh + ks8 * 32 + 32);
      v8s b1l = *(const v8s*)(cbl + ks8 * 32 + 32);
      const int ro = (mw3 * 16 + cl) * QPS + ks8 * 32 + q * 8;
      v8s a0h = *(const v8s*)&qphi[ro];
      v8s a0l = *(const v8s*)&qplo[ro];
      v8s a1h = *(const v8s*)&qphi[ro + 32];
      v8s a1l = *(const v8s*)&qplo[ro + 32];
      oaccA = MFMA(a0h, b0h, oaccA);
      oaccA = MFMA(a0h, b0l, oaccA);
      oaccA = MFMA(a0l, b0h, oaccA);
      oaccB = MFMA(a1h, b1h, oaccB);
      oaccB = MFMA(a1h, b1l, oaccB);
      oaccB = MFMA(a1l, b1h, oaccB);
    }
#pragma unroll
    for (int r = 0; r < 4; ++r) {
      int row = mw3 * 16 + q * 4 + r;
      float di = 1.0f / (dpart[0][row] + dpart[1][row] + dpart[2][row] +
                         dpart[3][row]);
      souts[row * OS + et3 * 16 + cl] = (oaccA[r] + oaccB[r]) * di;
    }
    __syncthreads();  // (3) souts ready
    {  // coalesced 32x64 tile store
      const int row = t >> 4, eo = (t & 15) * 4;
      float4 rr = *(const float4*)&souts[row * OS + eo];
      *(float4*)(out + ((size_t)(head * NSEQ + row0 + row)) * DHEAD + eo) = rr;
    }
    // no trailing barrier: next overwrites of qp/souts are behind (1)/(2)
  }
}

extern "C" void kernel_launch(void* const* d_in, const int* in_sizes, int n_in,
                              void* d_out, int out_size, void* d_ws, size_t ws_size,
                              hipStream_t stream) {
  (void)in_sizes; (void)n_in; (void)out_size; (void)ws_size;
  const float* q = (const float*)d_in[0];
  const float* k = (const float*)d_in[1];
  const float* v = (const float*)d_in[2];
  const float* proj = (const float*)d_in[3];
  float* out = (float*)d_out;
  unsigned char* ws = (unsigned char*)d_ws;
  unsigned* kmax_u = (unsigned*)ws;                    // @0
  float* ksum = (float*)(ws + 256);                    // 32 KB
  float* ctx = (float*)(ws + 33024);                   // 2 MB
  ushort* P2hi = (ushort*)(ws + 2130176);              // 32 KB
  ushort* P2lo = (ushort*)(ws + 2162944);              // 32 KB
  ushort* ctxThi = (ushort*)(ws + 2195712);            // 1 MB
  ushort* ctxTlo = (ushort*)(ws + 3244288);            // 1 MB -> end 4292864
  hipMemsetAsync(d_ws, 0, 2130176, stream);  // kmax_u + ksum + ctx
  hipLaunchKernelGGL(prep_kernel, dim3(64), dim3(256), 0, stream, proj, P2hi, P2lo);
  hipLaunchKernelGGL(kmax_kernel, dim3(512), dim3(512), 0, stream, k, P2hi,
                     kmax_u);
  hipLaunchKernelGGL(kctx_kernel, dim3(512), dim3(512), 0, stream, k, v, P2hi,
                     P2lo, kmax_u, ksum, ctx);
  hipLaunchKernelGGL(ctxprep_kernel, dim3(128), dim3(256), 0, stream, ctx,
                     ctxThi, ctxTlo);
  hipLaunchKernelGGL(qout_kernel, dim3(512), dim3(512), 0, stream, q, P2hi,
                     P2lo, ksum, ctxThi, ctxTlo, out);
}